// Round 2
// baseline (126.185 us; speedup 1.0000x reference)
//
#include <hip/hip_runtime.h>

// ConvTranspose3d (2,64,32^3) fp32 -> (2,32,66^3), stride2 pad1 outpad1 dil2 k3.
// Odd-grid MFMA: out[n,co,2dp+1,2hp+1,2wp+1] = bias[co] +
//   sum_{ci,kd,kh,kw} x[n,ci,dp+1-kd,hp+1-kh,wp+1-kw] * w[ci,co,kd,kh,kw]
// R15: rolling-dp blocks. Grid 512 (all resident, 2 blocks/CU), each block
// does 2 consecutive dp units sharing 2 of 3 id-groups in a 4-slot LDS ring.
// Unit1's one new group is prefetched to regs before unit0's MFMA and
// ds-written during it. Split-K reduce is 2-pass in the dead slot (12 KB).
// MFMA core / C-D map / output coverage identical to verified R14.

#define DOUT 66
#define PL (DOUT*DOUT)                  // 4356 floats/plane
#define ROW_B 4352                      // bytes per (id,ih) LDS row
#define SLOT_B 17408                    // 4 ih-rows = one id-group

typedef _Float16 half8   __attribute__((ext_vector_type(8)));
typedef float    floatx16 __attribute__((ext_vector_type(16)));
typedef float    floatx4  __attribute__((ext_vector_type(4)));
typedef float    floatx2  __attribute__((ext_vector_type(2)));

// ---- k1: w-pack. wA[cc 4][tap 27][lane 64][8 f16]; lane=co+32*khalf ----
__global__ void __launch_bounds__(256) wprep(const float* __restrict__ w,
                                             _Float16* __restrict__ wA)
{
    int o = blockIdx.x * 256 + threadIdx.x;   // < 55296 = 216*256
    int j = o & 7;
    int tmp = o >> 3;
    int lane = tmp & 63;
    int g = tmp >> 6;
    int cc = g / 27, tap = g - cc * 27;
    int co = lane & 31, khalf = lane >> 5;
    int ci = cc * 16 + khalf * 8 + j;
    wA[o] = (_Float16)w[ci * 864 + co * 27 + tap];
}

// ---- k2: fused repack + conv, 2 rolling dp units per block ----
__global__ void __launch_bounds__(256, 2) convt(
    const float* __restrict__ x, const _Float16* __restrict__ wA,
    const float* __restrict__ bias, float* __restrict__ out)
{
    __shared__ __align__(16) unsigned char xlds[4 * SLOT_B];   // 69632 B

    const int tid  = threadIdx.x;
    const int lane = tid & 63;
    const int wv   = tid >> 6;           // wave = K chunk (16 ci)

    unsigned b = blockIdx.x;             // 512: xcd(3) | hq2(2) | dpair(4)
    const unsigned xcd = b & 7u;
    const int n   = (int)(xcd & 1u);
    const unsigned rest = b >> 3;        // 0..63
    const int hq2   = (int)(rest & 3u);
    const int dpair = (int)(rest >> 2);  // 0..15
    const int hpg = (int)((xcd >> 1) * 4 + hq2);   // 0..15
    const int hpb = hpg * 2;
    const int dp0 = dpair * 2;           // units: dp0, dp0+1

    // slot s holds id = dp0-1+s, rows ih = hpb-1..hpb+2
    const float* xn = x + (size_t)n * 2097152;
    const int gq  = tid & 7;             // iw quad (iw = 4*gq..4*gq+3)
    const int ccg = (tid >> 3) & 7;      // ci group of 8
    const int ihl = wv;                  // row within group
    const int ih  = hpb - 1 + ihl;
    const bool ihok = (unsigned)ih < 32u;

    // ---- staging helpers (one 256-task pass per group) ----
    auto stage = [&](int slot, int id) {
        unsigned char* dst = xlds + slot * SLOT_B + ihl * ROW_B
                           + ccg * 544 + (gq * 4 + 1) * 16;
        if (ihok & ((unsigned)id < 32u)) {
            const float* src = xn + ccg * 262144 + (id * 32 + ih) * 32 + gq * 4;
            floatx4 f[8];
            #pragma unroll
            for (int j = 0; j < 8; ++j) f[j] = *(const floatx4*)(src + j * 32768);
            #pragma unroll
            for (int m = 0; m < 4; ++m) {
                unsigned p0 = __builtin_bit_cast(unsigned,
                    __builtin_amdgcn_cvt_pkrtz(f[0][m], f[1][m]));
                unsigned p1 = __builtin_bit_cast(unsigned,
                    __builtin_amdgcn_cvt_pkrtz(f[2][m], f[3][m]));
                unsigned p2 = __builtin_bit_cast(unsigned,
                    __builtin_amdgcn_cvt_pkrtz(f[4][m], f[5][m]));
                unsigned p3 = __builtin_bit_cast(unsigned,
                    __builtin_amdgcn_cvt_pkrtz(f[6][m], f[7][m]));
                *(uint4*)(dst + m * 16) = make_uint4(p0, p1, p2, p3);
            }
        } else {
            #pragma unroll
            for (int m = 0; m < 4; ++m)
                *(uint4*)(dst + m * 16) = make_uint4(0, 0, 0, 0);
        }
        if (tid < 64) {                  // halo iwl 0/33, 4 rows x 8 ccg x 2
            const int r2 = tid >> 4, rem = tid & 15;
            const int cg = rem >> 1, side = rem & 1;
            *(uint4*)(xlds + slot * SLOT_B + r2 * ROW_B + cg * 544
                      + (side ? 33 * 16 : 0)) = make_uint4(0, 0, 0, 0);
        }
    };

    // prefetch (split issue/write so MFMA hides the HBM latency)
    floatx4 pf[8];
    bool pfv = false;
    auto pf_load = [&](int id) {
        pfv = ihok & ((unsigned)id < 32u);
        if (pfv) {
            const float* src = xn + ccg * 262144 + (id * 32 + ih) * 32 + gq * 4;
            #pragma unroll
            for (int j = 0; j < 8; ++j) pf[j] = *(const floatx4*)(src + j * 32768);
        }
    };
    auto pf_write = [&](int slot) {
        unsigned char* dst = xlds + slot * SLOT_B + ihl * ROW_B
                           + ccg * 544 + (gq * 4 + 1) * 16;
        if (pfv) {
            #pragma unroll
            for (int m = 0; m < 4; ++m) {
                unsigned p0 = __builtin_bit_cast(unsigned,
                    __builtin_amdgcn_cvt_pkrtz(pf[0][m], pf[1][m]));
                unsigned p1 = __builtin_bit_cast(unsigned,
                    __builtin_amdgcn_cvt_pkrtz(pf[2][m], pf[3][m]));
                unsigned p2 = __builtin_bit_cast(unsigned,
                    __builtin_amdgcn_cvt_pkrtz(pf[4][m], pf[5][m]));
                unsigned p3 = __builtin_bit_cast(unsigned,
                    __builtin_amdgcn_cvt_pkrtz(pf[6][m], pf[7][m]));
                *(uint4*)(dst + m * 16) = make_uint4(p0, p1, p2, p3);
            }
        } else {
            #pragma unroll
            for (int m = 0; m < 4; ++m)
                *(uint4*)(dst + m * 16) = make_uint4(0, 0, 0, 0);
        }
        if (tid < 64) {
            const int r2 = tid >> 4, rem = tid & 15;
            const int cg = rem >> 1, side = rem & 1;
            *(uint4*)(xlds + slot * SLOT_B + r2 * ROW_B + cg * 544
                      + (side ? 33 * 16 : 0)) = make_uint4(0, 0, 0, 0);
        }
    };

    // ---- A fragments + bias preload (L2-hot) ----
    uint4 A[27];
    const _Float16* wl = wA + ((size_t)wv * 27 * 64 + lane) * 8;
    #pragma unroll
    for (int t = 0; t < 27; ++t) A[t] = *(const uint4*)(wl + t * 512);

    const int wp    = lane & 31;
    const int khalf = lane >> 5;
    const int cbase = (2 * wv + khalf) * 544 + wp * 16;

    float bv[16];
    #pragma unroll
    for (int r = 0; r < 16; ++r)
        bv[r] = bias[(r & 3) + 8 * (r >> 2) + 4 * khalf];

    // ---- initial staging: slots 0..2 (ids dp0-1, dp0, dp0+1) ----
    stage(0, dp0 - 1);
    stage(1, dp0);
    stage(2, dp0 + 1);
    __syncthreads();

    // ---- per-unit MFMA ----
    auto mfma_unit = [&](int base, floatx16& a0, floatx16& a1) {
        #pragma unroll
        for (int kd = 0; kd < 3; ++kd)
        #pragma unroll
        for (int kh = 0; kh < 3; ++kh)
        #pragma unroll
        for (int kw = 0; kw < 3; ++kw) {
            const int tap = (kd * 3 + kh) * 3 + kw;
            const uint4* bp0 = (const uint4*)(xlds + (base + 2 - kd) * SLOT_B
                               + (2 - kh) * ROW_B + cbase + (2 - kw) * 16);
            a0 = __builtin_amdgcn_mfma_f32_32x32x16_f16(
                __builtin_bit_cast(half8, A[tap]),
                __builtin_bit_cast(half8, bp0[0]), a0, 0, 0, 0);
            const uint4* bp1 = (const uint4*)((const char*)bp0 + ROW_B);
            acc1_step:
            a1 = __builtin_amdgcn_mfma_f32_32x32x16_f16(
                __builtin_bit_cast(half8, A[tap]),
                __builtin_bit_cast(half8, bp1[0]), a1, 0, 0, 0);
        }
    };

    // ---- per-unit reduce + store (scratch = dead slot u, 2-pass 12KB) ----
    auto reduce_store = [&](int u, int dp, floatx16& a0, floatx16& a1) {
        float* part = (float*)(xlds + u * SLOT_B);
        const int od = 2 * dp + 1;

        __syncthreads();                 // S1: MFMA reads of slot u done
        if (wv != 0) {
            #pragma unroll
            for (int r = 0; r < 16; ++r)
                part[(wv - 1) * 1024 + r * 64 + lane] = a0[r];
        }
        __syncthreads();                 // S2: tile0 parts visible
        float s[16];
        if (wv == 0) {
            #pragma unroll
            for (int r = 0; r < 16; ++r)
                s[r] = a0[r] + part[r * 64 + lane]
                             + part[1024 + r * 64 + lane]
                             + part[2048 + r * 64 + lane];
        }
        __syncthreads();                 // S3: pass-A reads done, scratch free
        if (wv != 1) {
            const int idx = (wv == 0) ? 0 : (wv - 1);
            #pragma unroll
            for (int r = 0; r < 16; ++r)
                part[idx * 1024 + r * 64 + lane] = a1[r];
        }
        if (wv == 0) {                   // store tile0 value row (overlaps)
            const int oh = 2 * hpb + 1;
            #pragma unroll
            for (int r = 0; r < 16; ++r) {
                const int co = (r & 3) + 8 * (r >> 2) + 4 * khalf;
                floatx2* orow = (floatx2*)(out +
                    ((size_t)(n * 32 + co) * DOUT + od) * PL + oh * DOUT);
                floatx2 vv = {bv[r], s[r] + bv[r]};
                __builtin_nontemporal_store(vv, orow + wp);
                if (wp == 31) {
                    floatx2 bb = {bv[r], bv[r]};
                    __builtin_nontemporal_store(bb, orow + 32);
                }
            }
        }
        __syncthreads();                 // S4: tile1 parts visible
        if (wv == 1) {
            float s1[16];
            #pragma unroll
            for (int r = 0; r < 16; ++r)
                s1[r] = a1[r] + part[r * 64 + lane]
                              + part[1024 + r * 64 + lane]
                              + part[2048 + r * 64 + lane];
            const int oh = 2 * hpb + 3;
            #pragma unroll
            for (int r = 0; r < 16; ++r) {
                const int co = (r & 3) + 8 * (r >> 2) + 4 * khalf;
                floatx2* orow = (floatx2*)(out +
                    ((size_t)(n * 32 + co) * DOUT + od) * PL + oh * DOUT);
                floatx2 vv = {bv[r], s1[r] + bv[r]};
                __builtin_nontemporal_store(vv, orow + wp);
                if (wp == 31) {
                    floatx2 bb = {bv[r], bv[r]};
                    __builtin_nontemporal_store(bb, orow + 32);
                }
            }
        } else if (wv >= 2) {
            // pure-bias rows for this dp (coverage identical to R14)
            const bool tails = (hpg == 15);
            const bool extra = (dp == 31);
            const int ohA = (wv == 2) ? 2 * hpb : 2 * hpb + 2;
            const int ohT = (wv == 2) ? 64 : 65;
            const int e0  = 4 * hpg + ((wv == 2) ? 0 : 2);
            auto putrow = [&](float* plane, int oh, floatx2 bb) {
                floatx2* rw = (floatx2*)(plane + oh * DOUT);
                __builtin_nontemporal_store(bb, rw + wp);
                if (wp == 31) __builtin_nontemporal_store(bb, rw + 32);
            };
            #pragma unroll
            for (int r = 0; r < 16; ++r) {
                const int co = (r & 3) + 8 * (r >> 2) + 4 * khalf;
                const floatx2 bb = {bv[r], bv[r]};
                float* pc    = out + (size_t)(n * 32 + co) * ((size_t)DOUT * PL);
                float* podd  = pc + (size_t)od * PL;
                float* peven = pc + (size_t)(od - 1) * PL;
                putrow(podd, ohA, bb);
                if (tails) putrow(podd, ohT, bb);
                putrow(peven, e0, bb);
                putrow(peven, e0 + 1, bb);
                if (tails) putrow(peven, ohT, bb);
                if (extra) {
                    float* p64 = pc + (size_t)64 * PL;
                    float* p65 = pc + (size_t)65 * PL;
                    putrow(p64, e0, bb);
                    putrow(p64, e0 + 1, bb);
                    putrow(p65, e0, bb);
                    putrow(p65, e0 + 1, bb);
                    if (tails) { putrow(p64, ohT, bb); putrow(p65, ohT, bb); }
                }
            }
        }
    };

    // ---- unit 0 (dp0): prefetch slot3 under the MFMAs ----
    {
        floatx16 a0 = {}, a1 = {};
        pf_load(dp0 + 2);                // issue early
        mfma_unit(0, a0, a1);
        pf_write(3);                     // lands before reduce barriers
        reduce_store(0, dp0, a0, a1);
    }
    // ---- unit 1 (dp0+1): slots 1..3 already resident ----
    {
        floatx16 a0 = {}, a1 = {};
        mfma_unit(1, a0, a1);
        reduce_store(1, dp0 + 1, a0, a1);
    }
}

extern "C" void kernel_launch(void* const* d_in, const int* in_sizes, int n_in,
                              void* d_out, int out_size, void* d_ws, size_t ws_size,
                              hipStream_t stream) {
    const float* x    = (const float*)d_in[0];
    const float* wgt  = (const float*)d_in[1];
    const float* bias = (const float*)d_in[2];
    float* out = (float*)d_out;
    _Float16* wA = (_Float16*)d_ws;      // 110592 B

    wprep<<<216, 256, 0, stream>>>(wgt, wA);
    convt<<<512, 256, 0, stream>>>(x, wA, bias, out);
}

// Round 3
// 107.612 us; speedup vs baseline: 1.1726x; 1.1726x over previous
//
#include <hip/hip_runtime.h>

// ConvTranspose3d (2,64,32^3) fp32 -> (2,32,66^3), stride2 pad1 outpad1 dil2 k3.
// Odd-grid MFMA: out[n,co,2dp+1,2hp+1,2wp+1] = bias[co] +
//   sum_{ci,kd,kh,kw} x[n,ci,dp+1-kd,hp+1-kh,wp+1-kw] * w[ci,co,kd,kh,kw]
// R16: span-coalesced stores. Values land in LDS (val[co][wp], +33 pad);
// each thread then writes full 1056-B contiguous spans (4 rows x 66 floats)
// per co as float4s, plain stores (L2 write-merge). All pure-bias spans
// (even planes, od64/65, tails) issue as a "bias blast" before the first
// barrier, overlapping the staging loads. MFMA core / split-K / C-D map
// identical to verified R15.

#define DOUT 66
#define PL (DOUT*DOUT)                  // 4356 floats/plane
#define ROW_B 4352                      // bytes per (id,ih) LDS row
#define SLOT_B 17408                    // 4 ih-rows = one id-group

typedef _Float16 half8   __attribute__((ext_vector_type(8)));
typedef float    floatx16 __attribute__((ext_vector_type(16)));
typedef float    floatx4  __attribute__((ext_vector_type(4)));

// ---- k1: w-pack. wA[cc 4][tap 27][lane 64][8 f16]; lane=co+32*khalf ----
__global__ void __launch_bounds__(256) wprep(const float* __restrict__ w,
                                             _Float16* __restrict__ wA)
{
    int o = blockIdx.x * 256 + threadIdx.x;   // < 55296 = 216*256
    int j = o & 7;
    int tmp = o >> 3;
    int lane = tmp & 63;
    int g = tmp >> 6;
    int cc = g / 27, tap = g - cc * 27;
    int co = lane & 31, khalf = lane >> 5;
    int ci = cc * 16 + khalf * 8 + j;
    wA[o] = (_Float16)w[ci * 864 + co * 27 + tap];
}

// ---- k2: fused repack + conv, 2 rolling dp units, span-coalesced output ----
__global__ void __launch_bounds__(256, 2) convt(
    const float* __restrict__ x, const _Float16* __restrict__ wA,
    const float* __restrict__ bias, float* __restrict__ out)
{
    __shared__ __align__(16) unsigned char xlds[4 * SLOT_B];   // 69632 B

    const int tid  = threadIdx.x;
    const int lane = tid & 63;
    const int wv   = tid >> 6;           // wave = K chunk (16 ci)

    unsigned b = blockIdx.x;             // 512: xcd(3) | hq2(2) | dpair(4)
    const unsigned xcd = b & 7u;
    const int n   = (int)(xcd & 1u);
    const unsigned rest = b >> 3;
    const int hq2   = (int)(rest & 3u);
    const int dpair = (int)(rest >> 2);  // 0..15
    const int hpg = (int)((xcd >> 1) * 4 + hq2);   // 0..15
    const int hpb = hpg * 2;
    const int dp0 = dpair * 2;           // units: dp0, dp0+1

    const float* xn = x + (size_t)n * 2097152;
    const int gq  = tid & 7;             // iw quad (iw = 4*gq..4*gq+3)
    const int ccg = (tid >> 3) & 7;      // ci group of 8
    const int ihl = wv;                  // row within group
    const int ih  = hpb - 1 + ihl;
    const bool ihok = (unsigned)ih < 32u;

    // store-role indices: thread owns co_s, lane-slice l8
    const int co_s = tid >> 3;           // 0..31
    const int l8   = tid & 7;

    // ---- staging helper (one 256-task pass per group) ----
    auto stage = [&](int slot, int id) {
        unsigned char* dst = xlds + slot * SLOT_B + ihl * ROW_B
                           + ccg * 544 + (gq * 4 + 1) * 16;
        if (ihok & ((unsigned)id < 32u)) {
            const float* src = xn + ccg * 262144 + (id * 32 + ih) * 32 + gq * 4;
            floatx4 f[8];
            #pragma unroll
            for (int j = 0; j < 8; ++j) f[j] = *(const floatx4*)(src + j * 32768);
            #pragma unroll
            for (int m = 0; m < 4; ++m) {
                unsigned p0 = __builtin_bit_cast(unsigned,
                    __builtin_amdgcn_cvt_pkrtz(f[0][m], f[1][m]));
                unsigned p1 = __builtin_bit_cast(unsigned,
                    __builtin_amdgcn_cvt_pkrtz(f[2][m], f[3][m]));
                unsigned p2 = __builtin_bit_cast(unsigned,
                    __builtin_amdgcn_cvt_pkrtz(f[4][m], f[5][m]));
                unsigned p3 = __builtin_bit_cast(unsigned,
                    __builtin_amdgcn_cvt_pkrtz(f[6][m], f[7][m]));
                *(uint4*)(dst + m * 16) = make_uint4(p0, p1, p2, p3);
            }
        } else {
            #pragma unroll
            for (int m = 0; m < 4; ++m)
                *(uint4*)(dst + m * 16) = make_uint4(0, 0, 0, 0);
        }
        if (tid < 64) {                  // halo iwl 0/33, 4 rows x 8 ccg x 2
            const int r2 = tid >> 4, rem = tid & 15;
            const int cg = rem >> 1, side = rem & 1;
            *(uint4*)(xlds + slot * SLOT_B + r2 * ROW_B + cg * 544
                      + (side ? 33 * 16 : 0)) = make_uint4(0, 0, 0, 0);
        }
    };

    // prefetch (issue early / write late)
    floatx4 pf[8];
    bool pfv = false;
    auto pf_load = [&](int id) {
        pfv = ihok & ((unsigned)id < 32u);
        if (pfv) {
            const float* src = xn + ccg * 262144 + (id * 32 + ih) * 32 + gq * 4;
            #pragma unroll
            for (int j = 0; j < 8; ++j) pf[j] = *(const floatx4*)(src + j * 32768);
        }
    };
    auto pf_write = [&](int slot) {
        unsigned char* dst = xlds + slot * SLOT_B + ihl * ROW_B
                           + ccg * 544 + (gq * 4 + 1) * 16;
        if (pfv) {
            #pragma unroll
            for (int m = 0; m < 4; ++m) {
                unsigned p0 = __builtin_bit_cast(unsigned,
                    __builtin_amdgcn_cvt_pkrtz(pf[0][m], pf[1][m]));
                unsigned p1 = __builtin_bit_cast(unsigned,
                    __builtin_amdgcn_cvt_pkrtz(pf[2][m], pf[3][m]));
                unsigned p2 = __builtin_bit_cast(unsigned,
                    __builtin_amdgcn_cvt_pkrtz(pf[4][m], pf[5][m]));
                unsigned p3 = __builtin_bit_cast(unsigned,
                    __builtin_amdgcn_cvt_pkrtz(pf[6][m], pf[7][m]));
                *(uint4*)(dst + m * 16) = make_uint4(p0, p1, p2, p3);
            }
        } else {
            #pragma unroll
            for (int m = 0; m < 4; ++m)
                *(uint4*)(dst + m * 16) = make_uint4(0, 0, 0, 0);
        }
        if (tid < 64) {
            const int r2 = tid >> 4, rem = tid & 15;
            const int cg = rem >> 1, side = rem & 1;
            *(uint4*)(xlds + slot * SLOT_B + r2 * ROW_B + cg * 544
                      + (side ? 33 * 16 : 0)) = make_uint4(0, 0, 0, 0);
        }
    };

    // ---- A fragments + bias preload (L2-hot) ----
    uint4 A[27];
    const _Float16* wl = wA + ((size_t)wv * 27 * 64 + lane) * 8;
    #pragma unroll
    for (int t = 0; t < 27; ++t) A[t] = *(const uint4*)(wl + t * 512);

    const int wp    = lane & 31;
    const int khalf = lane >> 5;
    const int cbase = (2 * wv + khalf) * 544 + wp * 16;

    const float bvc = bias[co_s];        // store-role bias
    const int nr    = (hpg == 15) ? 6 : 4;         // rows per span (tails folded)
    const int npass = (hpg == 15) ? 13 : 9;
    const int SP    = nr * 66 / 4;                 // float4s per span: 66 or 99

    auto bias_span = [&](float* base) {            // pure-bias contiguous span
        const floatx4 bb = {bvc, bvc, bvc, bvc};
        for (int p = 0; p < npass; ++p) {
            const int q = l8 + 8 * p;
            if (q < SP) *(floatx4*)(base + 4 * q) = bb;
        }
    };

    // ---- initial staging: slots 0..2 (ids dp0-1, dp0, dp0+1) ----
    stage(0, dp0 - 1);
    stage(1, dp0);
    stage(2, dp0 + 1);

    // ---- bias blast: all pure-bias spans, overlapping the load phase ----
    {
        #pragma unroll
        for (int u = 0; u < 2; ++u) {              // even planes 2*(dp0+u)
            float* pb = out + ((size_t)(n * 32 + co_s) * DOUT + 2 * (dp0 + u)) * PL
                        + 4 * hpg * DOUT;
            bias_span(pb);
        }
        if (dp0 == 30) {                           // planes 64, 65
            float* p64 = out + ((size_t)(n * 32 + co_s) * DOUT + 64) * PL
                         + 4 * hpg * DOUT;
            bias_span(p64);
            bias_span(p64 + PL);
        }
    }
    __syncthreads();

    // ---- per-unit MFMA (verified core) ----
    auto mfma_unit = [&](int base, floatx16& a0, floatx16& a1) {
        #pragma unroll
        for (int kd = 0; kd < 3; ++kd)
        #pragma unroll
        for (int kh = 0; kh < 3; ++kh)
        #pragma unroll
        for (int kw = 0; kw < 3; ++kw) {
            const int tap = (kd * 3 + kh) * 3 + kw;
            const uint4* bp0 = (const uint4*)(xlds + (base + 2 - kd) * SLOT_B
                               + (2 - kh) * ROW_B + cbase + (2 - kw) * 16);
            a0 = __builtin_amdgcn_mfma_f32_32x32x16_f16(
                __builtin_bit_cast(half8, A[tap]),
                __builtin_bit_cast(half8, bp0[0]), a0, 0, 0, 0);
            const uint4* bp1 = (const uint4*)((const char*)bp0 + ROW_B);
            a1 = __builtin_amdgcn_mfma_f32_32x32x16_f16(
                __builtin_bit_cast(half8, A[tap]),
                __builtin_bit_cast(half8, bp1[0]), a1, 0, 0, 0);
        }
    };

    // ---- split-K reduce -> val[co*33+wp] in LDS (dead slot u) ----
    // layout: scratch parts [0,12288); val0 [12288,16512); val1 [0,4224) (reuse)
    auto reduce_val = [&](int u, floatx16& a0, floatx16& a1) {
        float* scratch = (float*)(xlds + u * SLOT_B);
        float* val0    = (float*)(xlds + u * SLOT_B + 12288);
        float* val1    = scratch;
        __syncthreads();                 // S1: slot-u MFMA reads done
        if (wv != 0) {
            #pragma unroll
            for (int r = 0; r < 16; ++r)
                scratch[(wv - 1) * 1024 + r * 64 + lane] = a0[r];
        }
        __syncthreads();                 // S2: tile0 parts visible
        if (wv == 0) {
            #pragma unroll
            for (int r = 0; r < 16; ++r) {
                float s = a0[r] + scratch[r * 64 + lane]
                                + scratch[1024 + r * 64 + lane]
                                + scratch[2048 + r * 64 + lane];
                const int co = (r & 3) + 8 * (r >> 2) + 4 * khalf;
                val0[co * 33 + wp] = s;
            }
        }
        __syncthreads();                 // S3: pass-A scratch reads done
        if (wv != 1) {
            const int idx = (wv == 0) ? 0 : wv - 1;
            #pragma unroll
            for (int r = 0; r < 16; ++r)
                scratch[idx * 1024 + r * 64 + lane] = a1[r];
        }
        __syncthreads();                 // S4: tile1 parts visible
        if (wv == 1) {
            // buffer ALL reads before any write (val1 aliases scratch)
            float s[16];
            #pragma unroll
            for (int r = 0; r < 16; ++r)
                s[r] = a1[r] + scratch[r * 64 + lane]
                             + scratch[1024 + r * 64 + lane]
                             + scratch[2048 + r * 64 + lane];
            #pragma unroll
            for (int r = 0; r < 16; ++r) {
                const int co = (r & 3) + 8 * (r >> 2) + 4 * khalf;
                val1[co * 33 + wp] = s[r];
            }
        }
        __syncthreads();                 // S5: vals ready for span store
    };

    // ---- value-span store: contiguous 4(6)-row span per co, float4 lanes ----
    auto store_A = [&](int u, int dp) {
        const float* val0 = (const float*)(xlds + u * SLOT_B + 12288);
        const float* val1 = (const float*)(xlds + u * SLOT_B);
        float* base = out + ((size_t)(n * 32 + co_s) * DOUT + 2 * dp + 1) * PL
                      + 4 * hpg * DOUT;
        for (int p = 0; p < npass; ++p) {
            const int q = l8 + 8 * p;
            if (q >= SP) continue;
            floatx4 o;
            #pragma unroll
            for (int j = 0; j < 4; ++j) {
                const int e = 4 * q + j;             // 0..395
                const int rl = (e >= 330) ? 5 : (e >= 264) ? 4 : (e >= 198) ? 3 :
                               (e >= 132) ? 2 : (e >= 66) ? 1 : 0;
                const int ow = e - rl * 66;
                float v = bvc;
                if ((rl == 1 || rl == 3) && (ow & 1) && ow < 65) {
                    const float* vt = (rl == 1) ? val0 : val1;
                    v += vt[co_s * 33 + (ow >> 1)];
                }
                o[j] = v;
            }
            *(floatx4*)(base + 4 * q) = o;
        }
    };

    // ---- unit 0 (dp0): prefetch slot3 under the MFMAs ----
    {
        floatx16 a0 = {}, a1 = {};
        pf_load(dp0 + 2);
        mfma_unit(0, a0, a1);
        pf_write(3);
        reduce_val(0, a0, a1);
        store_A(0, dp0);
    }
    // ---- unit 1 (dp0+1): slots 1..3 resident ----
    {
        floatx16 a0 = {}, a1 = {};
        mfma_unit(1, a0, a1);
        reduce_val(1, a0, a1);
        store_A(1, dp0 + 1);
    }
}

extern "C" void kernel_launch(void* const* d_in, const int* in_sizes, int n_in,
                              void* d_out, int out_size, void* d_ws, size_t ws_size,
                              hipStream_t stream) {
    const float* x    = (const float*)d_in[0];
    const float* wgt  = (const float*)d_in[1];
    const float* bias = (const float*)d_in[2];
    float* out = (float*)d_out;
    _Float16* wA = (_Float16*)d_ws;      // 110592 B

    wprep<<<216, 256, 0, stream>>>(wgt, wA);
    convt<<<512, 256, 0, stream>>>(x, wA, bias, out);
}

// Round 4
// 105.375 us; speedup vs baseline: 1.1975x; 1.0212x over previous
//
#include <hip/hip_runtime.h>

// ConvTranspose3d (2,64,32^3) fp32 -> (2,32,66^3), stride2 pad1 outpad1 dil2 k3.
// Odd-grid MFMA: out[n,co,2dp+1,2hp+1,2wp+1] = bias[co] +
//   sum_{ci,kd,kh,kw} x[n,ci,dp+1-kd,hp+1-kh,wp+1-kw] * w[ci,co,kd,kh,kw]
// R17: no split-K. 4 hp rows/block, one wave per hp tile, each wave loops
// all 4 ci-chunks (A[27] reloaded per chunk, L2-hot). 3 barriers/block
// (was 11), no reduce scratch. Output = 8-row contiguous spans (2112 B/co,
// 2640 at hpg7 tail) composed from val[hp][co][wp] in LDS; even-plane +
// od64/65 bias blasts overlap staging. Stage layout / MFMA / C-D map
// verbatim from the verified R16 kernel.

#define DOUT 66
#define PL (DOUT*DOUT)                  // 4356 floats/plane
#define ROW_B 4352                      // bytes per (id,ih) LDS row
#define IDG_B (6*ROW_B)                 // 6 ih-rows per id group = 26112 B

typedef _Float16 half8   __attribute__((ext_vector_type(8)));
typedef float    floatx16 __attribute__((ext_vector_type(16)));
typedef float    floatx4  __attribute__((ext_vector_type(4)));

// ---- k1: w-pack. wA[cc 4][tap 27][lane 64][8 f16]; lane=co+32*khalf ----
__global__ void __launch_bounds__(256) wprep(const float* __restrict__ w,
                                             _Float16* __restrict__ wA)
{
    int o = blockIdx.x * 256 + threadIdx.x;   // < 55296 = 216*256
    int j = o & 7;
    int tmp = o >> 3;
    int lane = tmp & 63;
    int g = tmp >> 6;
    int cc = g / 27, tap = g - cc * 27;
    int co = lane & 31, khalf = lane >> 5;
    int ci = cc * 16 + khalf * 8 + j;
    wA[o] = (_Float16)w[ci * 864 + co * 27 + tap];
}

// ---- k2: fused repack + conv, 4 hp tiles (1/wave), span stores ----
__global__ void __launch_bounds__(256, 2) convt(
    const float* __restrict__ x, const _Float16* __restrict__ wA,
    const float* __restrict__ bias, float* __restrict__ out)
{
    __shared__ __align__(16) unsigned char xlds[3 * IDG_B];   // 78336 B

    const int tid  = threadIdx.x;
    const int lane = tid & 63;
    const int wv   = tid >> 6;           // wave = hp tile index

    unsigned b = blockIdx.x;             // 512: xcd(3) | hsub(1) | dp(5)
    const unsigned xcd = b & 7u;
    const int n     = (int)(xcd & 1u);
    const unsigned rest = b >> 3;
    const int hpg   = (int)((xcd >> 1) * 2 + (rest & 1u));   // 0..7
    const int dp    = (int)(rest >> 1);                      // 0..31
    const int hpb   = hpg * 4;           // hp = hpb..hpb+3

    const float* xn = x + (size_t)n * 2097152;

    // store-role indices
    const int co_s = tid >> 3;           // 0..31
    const int l8   = tid & 7;
    const float bvc = bias[co_s];
    const floatx4 bb4 = {bvc, bvc, bvc, bvc};

    // ---- staging: 18 rows (id 3 x ih 6), 1152 tasks, wave-uniform rows ----
    // task t: r = t>>6 (id_l = r/6, ihl = r%6), ccg = (t>>3)&7, gq = t&7
    {
        for (int t = tid; t < 1152; t += 256) {
            const int r   = t >> 6;
            const int ccg = (t >> 3) & 7;
            const int gq  = t & 7;
            const int id_l = r / 6, ihl = r - 6 * id_l;
            const int id = dp - 1 + id_l;
            const int ih = hpb - 1 + ihl;
            unsigned char* dst = xlds + (id_l * 6 + ihl) * ROW_B
                               + ccg * 544 + (gq * 4 + 1) * 16;
            if (((unsigned)id < 32u) & ((unsigned)ih < 32u)) {
                const float* src = xn + ccg * 262144 + (id * 32 + ih) * 32 + gq * 4;
                floatx4 f[8];
                #pragma unroll
                for (int j = 0; j < 8; ++j) f[j] = *(const floatx4*)(src + j * 32768);
                #pragma unroll
                for (int m = 0; m < 4; ++m) {
                    unsigned p0 = __builtin_bit_cast(unsigned,
                        __builtin_amdgcn_cvt_pkrtz(f[0][m], f[1][m]));
                    unsigned p1 = __builtin_bit_cast(unsigned,
                        __builtin_amdgcn_cvt_pkrtz(f[2][m], f[3][m]));
                    unsigned p2 = __builtin_bit_cast(unsigned,
                        __builtin_amdgcn_cvt_pkrtz(f[4][m], f[5][m]));
                    unsigned p3 = __builtin_bit_cast(unsigned,
                        __builtin_amdgcn_cvt_pkrtz(f[6][m], f[7][m]));
                    *(uint4*)(dst + m * 16) = make_uint4(p0, p1, p2, p3);
                }
            } else {
                #pragma unroll
                for (int m = 0; m < 4; ++m)
                    *(uint4*)(dst + m * 16) = make_uint4(0, 0, 0, 0);
            }
        }
        // halo iwl 0/33: 18 rows x 8 ccg x 2 sides = 288 cells
        for (int h = tid; h < 288; h += 256) {
            const int r = h >> 4, rem = h & 15;
            const int cg = rem >> 1, side = rem & 1;
            *(uint4*)(xlds + r * ROW_B + cg * 544 + (side ? 33 * 16 : 0)) =
                make_uint4(0, 0, 0, 0);
        }
    }

    // ---- bias blast: even plane 2dp (+ planes 64/65 at dp31), overlaps loads ----
    {
        const int nq = (hpg == 7) ? 165 : 132;     // float4s in span (8 or 10 rows)
        float* eb = out + ((size_t)(n * 32 + co_s) * DOUT + 2 * dp) * PL
                    + 8 * hpg * DOUT;
        for (int q = l8; q < nq; q += 8) *(floatx4*)(eb + 4 * q) = bb4;
        if (dp == 31) {
            float* p64 = out + ((size_t)(n * 32 + co_s) * DOUT + 64) * PL
                         + 8 * hpg * DOUT;
            for (int q = l8; q < nq; q += 8) *(floatx4*)(p64 + 4 * q) = bb4;
            float* p65 = p64 + PL;
            for (int q = l8; q < nq; q += 8) *(floatx4*)(p65 + 4 * q) = bb4;
        }
    }
    __syncthreads();                                 // B1: LDS staged

    // ---- MFMA: wave wv owns hp = hpb+wv; loop all 4 ci chunks ----
    const int wp    = lane & 31;
    const int khalf = lane >> 5;

    floatx16 acc = {};
    #pragma unroll
    for (int cc = 0; cc < 4; ++cc) {
        uint4 A[27];
        const _Float16* wl = wA + ((size_t)cc * 27 * 64 + lane) * 8;
        #pragma unroll
        for (int t = 0; t < 27; ++t) A[t] = *(const uint4*)(wl + t * 512);
        const int cb = (2 * cc + khalf) * 544 + wp * 16;
        #pragma unroll
        for (int kd = 0; kd < 3; ++kd)
        #pragma unroll
        for (int kh = 0; kh < 3; ++kh)
        #pragma unroll
        for (int kw = 0; kw < 3; ++kw) {
            const int tap = (kd * 3 + kh) * 3 + kw;
            const uint4* bp = (const uint4*)(xlds
                + ((2 - kd) * 6 + (wv + 2 - kh)) * ROW_B + cb + (2 - kw) * 16);
            acc = __builtin_amdgcn_mfma_f32_32x32x16_f16(
                __builtin_bit_cast(half8, A[tap]),
                __builtin_bit_cast(half8, bp[0]), acc, 0, 0, 0);
        }
    }

    // ---- vals to LDS: val[hp_local 4][co 32][wp 32 +pad] ----
    __syncthreads();                                 // B2: MFMA reads done
    float* val = (float*)xlds;                       // 4*32*33*4 = 16896 B
    #pragma unroll
    for (int r = 0; r < 16; ++r) {
        const int co = (r & 3) + 8 * (r >> 2) + 4 * khalf;   // verified C/D map
        val[((size_t)wv * 32 + co) * 33 + wp] = acc[r];
    }
    __syncthreads();                                 // B3: vals visible

    // ---- odd-plane span store: 8 rows (2112 B) per co, values interleaved ----
    {
        float* base = out + ((size_t)(n * 32 + co_s) * DOUT + 2 * dp + 1) * PL
                      + 8 * hpg * DOUT;
        #pragma unroll
        for (int p = 0; p < 17; ++p) {
            const int q = l8 + 8 * p;
            if (q < 132) {
                floatx4 o;
                #pragma unroll
                for (int j = 0; j < 4; ++j) {
                    const int e = 4 * q + j;          // 0..527
                    const int rl = e / 66;            // span row 0..7
                    const int ow = e - rl * 66;
                    float v = bvc;
                    if ((rl & 1) && (ow & 1) && ow < 65)
                        v += val[(((rl >> 1) * 32) + co_s) * 33 + (ow >> 1)];
                    o[j] = v;
                }
                *(floatx4*)(base + 4 * q) = o;
            }
        }
        if (hpg == 7) {                               // tail rows 64,65: bias only
            for (int p = 0; p < 5; ++p) {
                const int q = 132 + l8 + 8 * p;
                if (q < 165) *(floatx4*)(base + 4 * q) = bb4;
            }
        }
    }
}

extern "C" void kernel_launch(void* const* d_in, const int* in_sizes, int n_in,
                              void* d_out, int out_size, void* d_ws, size_t ws_size,
                              hipStream_t stream) {
    const float* x    = (const float*)d_in[0];
    const float* wgt  = (const float*)d_in[1];
    const float* bias = (const float*)d_in[2];
    float* out = (float*)d_out;
    _Float16* wA = (_Float16*)d_ws;      // 110592 B

    wprep<<<216, 256, 0, stream>>>(wgt, wA);
    convt<<<512, 256, 0, stream>>>(x, wA, bias, out);
}

// Round 5
// 102.711 us; speedup vs baseline: 1.2285x; 1.0259x over previous
//
#include <hip/hip_runtime.h>

// ConvTranspose3d (2,64,32^3) fp32 -> (2,32,66^3), stride2 pad1 outpad1 dil2 k3.
// Odd-grid MFMA: out[n,co,2dp+1,2hp+1,2wp+1] = bias[co] +
//   sum_{ci,kd,kh,kw} x[n,ci,dp+1-kd,hp+1-kh,wp+1-kw] * w[ci,co,kd,kh,kw]
// R18 = R17 with one change: NO global store is issued before any
// __syncthreads(). __syncthreads lowers to s_waitcnt vmcnt(0)+s_barrier,
// and vmcnt counts stores -- pre-barrier stores put the full store-drain
// on the critical path (the hidden ~15 us in R15-R17). All stores (odd-
// plane values, even-plane bias, od64/65, tails) now issue after the last
// barrier and drain only at endpgm (pure write-pipe tail = the floor).
// Stage layout / MFMA core / C-D map verbatim from verified R17.

#define DOUT 66
#define PL (DOUT*DOUT)                  // 4356 floats/plane
#define ROW_B 4352                      // bytes per (id,ih) LDS row
#define IDG_B (6*ROW_B)                 // 6 ih-rows per id group = 26112 B

typedef _Float16 half8   __attribute__((ext_vector_type(8)));
typedef float    floatx16 __attribute__((ext_vector_type(16)));
typedef float    floatx4  __attribute__((ext_vector_type(4)));

// ---- k1: w-pack. wA[cc 4][tap 27][lane 64][8 f16]; lane=co+32*khalf ----
__global__ void __launch_bounds__(256) wprep(const float* __restrict__ w,
                                             _Float16* __restrict__ wA)
{
    int o = blockIdx.x * 256 + threadIdx.x;   // < 55296 = 216*256
    int j = o & 7;
    int tmp = o >> 3;
    int lane = tmp & 63;
    int g = tmp >> 6;
    int cc = g / 27, tap = g - cc * 27;
    int co = lane & 31, khalf = lane >> 5;
    int ci = cc * 16 + khalf * 8 + j;
    wA[o] = (_Float16)w[ci * 864 + co * 27 + tap];
}

// ---- k2: fused repack + conv, 4 hp tiles (1/wave), stores after barriers ----
__global__ void __launch_bounds__(256, 2) convt(
    const float* __restrict__ x, const _Float16* __restrict__ wA,
    const float* __restrict__ bias, float* __restrict__ out)
{
    __shared__ __align__(16) unsigned char xlds[3 * IDG_B];   // 78336 B

    const int tid  = threadIdx.x;
    const int lane = tid & 63;
    const int wv   = tid >> 6;           // wave = hp tile index

    unsigned b = blockIdx.x;             // 512: xcd(3) | hsub(1) | dp(5)
    const unsigned xcd = b & 7u;
    const int n     = (int)(xcd & 1u);
    const unsigned rest = b >> 3;
    const int hpg   = (int)((xcd >> 1) * 2 + (rest & 1u));   // 0..7
    const int dp    = (int)(rest >> 1);                      // 0..31
    const int hpb   = hpg * 4;           // hp = hpb..hpb+3

    const float* xn = x + (size_t)n * 2097152;

    // store-role indices
    const int co_s = tid >> 3;           // 0..31
    const int l8   = tid & 7;
    const float bvc = bias[co_s];
    const floatx4 bb4 = {bvc, bvc, bvc, bvc};

    // ---- staging: 18 rows (id 3 x ih 6), 1152 tasks, wave-uniform rows ----
    {
        for (int t = tid; t < 1152; t += 256) {
            const int r   = t >> 6;
            const int ccg = (t >> 3) & 7;
            const int gq  = t & 7;
            const int id_l = r / 6, ihl = r - 6 * id_l;
            const int id = dp - 1 + id_l;
            const int ih = hpb - 1 + ihl;
            unsigned char* dst = xlds + (id_l * 6 + ihl) * ROW_B
                               + ccg * 544 + (gq * 4 + 1) * 16;
            if (((unsigned)id < 32u) & ((unsigned)ih < 32u)) {
                const float* src = xn + ccg * 262144 + (id * 32 + ih) * 32 + gq * 4;
                floatx4 f[8];
                #pragma unroll
                for (int j = 0; j < 8; ++j) f[j] = *(const floatx4*)(src + j * 32768);
                #pragma unroll
                for (int m = 0; m < 4; ++m) {
                    unsigned p0 = __builtin_bit_cast(unsigned,
                        __builtin_amdgcn_cvt_pkrtz(f[0][m], f[1][m]));
                    unsigned p1 = __builtin_bit_cast(unsigned,
                        __builtin_amdgcn_cvt_pkrtz(f[2][m], f[3][m]));
                    unsigned p2 = __builtin_bit_cast(unsigned,
                        __builtin_amdgcn_cvt_pkrtz(f[4][m], f[5][m]));
                    unsigned p3 = __builtin_bit_cast(unsigned,
                        __builtin_amdgcn_cvt_pkrtz(f[6][m], f[7][m]));
                    *(uint4*)(dst + m * 16) = make_uint4(p0, p1, p2, p3);
                }
            } else {
                #pragma unroll
                for (int m = 0; m < 4; ++m)
                    *(uint4*)(dst + m * 16) = make_uint4(0, 0, 0, 0);
            }
        }
        // halo iwl 0/33: 18 rows x 8 ccg x 2 sides = 288 cells
        for (int h = tid; h < 288; h += 256) {
            const int r = h >> 4, rem = h & 15;
            const int cg = rem >> 1, side = rem & 1;
            *(uint4*)(xlds + r * ROW_B + cg * 544 + (side ? 33 * 16 : 0)) =
                make_uint4(0, 0, 0, 0);
        }
    }
    __syncthreads();                                 // B1: LDS staged (loads only)

    // ---- MFMA: wave wv owns hp = hpb+wv; loop all 4 ci chunks ----
    const int wp    = lane & 31;
    const int khalf = lane >> 5;

    floatx16 acc = {};
    #pragma unroll
    for (int cc = 0; cc < 4; ++cc) {
        uint4 A[27];
        const _Float16* wl = wA + ((size_t)cc * 27 * 64 + lane) * 8;
        #pragma unroll
        for (int t = 0; t < 27; ++t) A[t] = *(const uint4*)(wl + t * 512);
        const int cb = (2 * cc + khalf) * 544 + wp * 16;
        #pragma unroll
        for (int kd = 0; kd < 3; ++kd)
        #pragma unroll
        for (int kh = 0; kh < 3; ++kh)
        #pragma unroll
        for (int kw = 0; kw < 3; ++kw) {
            const int tap = (kd * 3 + kh) * 3 + kw;
            const uint4* bp = (const uint4*)(xlds
                + ((2 - kd) * 6 + (wv + 2 - kh)) * ROW_B + cb + (2 - kw) * 16);
            acc = __builtin_amdgcn_mfma_f32_32x32x16_f16(
                __builtin_bit_cast(half8, A[tap]),
                __builtin_bit_cast(half8, bp[0]), acc, 0, 0, 0);
        }
    }

    // ---- vals to LDS: val[hp_local 4][co 32][wp 32 +pad] ----
    __syncthreads();                                 // B2: MFMA reads done
    float* val = (float*)xlds;                       // 4*32*33*4 = 16896 B
    #pragma unroll
    for (int r = 0; r < 16; ++r) {
        const int co = (r & 3) + 8 * (r >> 2) + 4 * khalf;   // verified C/D map
        val[((size_t)wv * 32 + co) * 33 + wp] = acc[r];
    }
    __syncthreads();                                 // B3: vals visible

    // ======== ALL global stores below this line (drain only at endpgm) ====

    // ---- odd-plane span store: 8 rows (2112 B) per co, values interleaved ----
    {
        float* base = out + ((size_t)(n * 32 + co_s) * DOUT + 2 * dp + 1) * PL
                      + 8 * hpg * DOUT;
        #pragma unroll
        for (int p = 0; p < 17; ++p) {
            const int q = l8 + 8 * p;
            if (q < 132) {
                floatx4 o;
                #pragma unroll
                for (int j = 0; j < 4; ++j) {
                    const int e = 4 * q + j;          // 0..527
                    const int rl = e / 66;            // span row 0..7
                    const int ow = e - rl * 66;
                    float v = bvc;
                    if ((rl & 1) && (ow & 1) && ow < 65)
                        v += val[(((rl >> 1) * 32) + co_s) * 33 + (ow >> 1)];
                    o[j] = v;
                }
                *(floatx4*)(base + 4 * q) = o;
            }
        }
        if (hpg == 7) {                               // tail rows 64,65: bias only
            for (int p = 0; p < 5; ++p) {
                const int q = 132 + l8 + 8 * p;
                if (q < 165) *(floatx4*)(base + 4 * q) = bb4;
            }
        }
    }

    // ---- even-plane bias span (+ planes 64/65 at dp31) ----
    {
        const int nq = (hpg == 7) ? 165 : 132;       // float4s in span
        float* eb = out + ((size_t)(n * 32 + co_s) * DOUT + 2 * dp) * PL
                    + 8 * hpg * DOUT;
        for (int q = l8; q < nq; q += 8) *(floatx4*)(eb + 4 * q) = bb4;
        if (dp == 31) {
            float* p64 = out + ((size_t)(n * 32 + co_s) * DOUT + 64) * PL
                         + 8 * hpg * DOUT;
            for (int q = l8; q < nq; q += 8) *(floatx4*)(p64 + 4 * q) = bb4;
            float* p65 = p64 + PL;
            for (int q = l8; q < nq; q += 8) *(floatx4*)(p65 + 4 * q) = bb4;
        }
    }
}

extern "C" void kernel_launch(void* const* d_in, const int* in_sizes, int n_in,
                              void* d_out, int out_size, void* d_ws, size_t ws_size,
                              hipStream_t stream) {
    const float* x    = (const float*)d_in[0];
    const float* wgt  = (const float*)d_in[1];
    const float* bias = (const float*)d_in[2];
    float* out = (float*)d_out;
    _Float16* wA = (_Float16*)d_ws;      // 110592 B

    wprep<<<216, 256, 0, stream>>>(wgt, wA);
    convt<<<512, 256, 0, stream>>>(x, wA, bias, out);
}